// Round 4
// baseline (112.988 us; speedup 1.0000x reference)
//
#include <hip/hip_runtime.h>
#include <math.h>

// FutureEncoder: B=4, S=2048, D=1024, FUTURE_K=32, fp32 in/out.
// R4: G=8 tokens/block (1024 blocks, 4/CU). Split-fp16 MFMA scores
// (native v_cvt_f16_f32, 3-MFMA hi/lo, lo*lo dropped), LDS reduce+softmax,
// D-split fp32 PV (wave owns a 256-dim slice for all 8 tokens).

constexpr int S_CONST = 2048;
constexpr int D = 1024;
constexpr int G = 8;               // tokens per block
constexpr int JT = 3;              // 3 column tiles -> 48 band columns
constexpr int JW = 48;
constexpr int JMAX = 38;           // largest useful j (token 7, k=31)
constexpr int SCP = G * 49;        // per-wave partial-score stride (pad 49)

typedef _Float16 half8 __attribute__((ext_vector_type(8)));
typedef float f32x4  __attribute__((ext_vector_type(4)));

// 8 fp32 -> fp16 hi + fp16 lo (hi+lo ~ exact to 2^-21 rel)
__device__ inline void cvt8(const float* p, half8& hi, half8& lo) {
    float4 x0 = *(const float4*)p;
    float4 x1 = *(const float4*)(p + 4);
    float xs[8] = {x0.x, x0.y, x0.z, x0.w, x1.x, x1.y, x1.z, x1.w};
    #pragma unroll
    for (int e = 0; e < 8; ++e) {
        _Float16 hv = (_Float16)xs[e];
        hi[e] = hv;
        lo[e] = (_Float16)(xs[e] - (float)hv);
    }
}

__global__ __launch_bounds__(256, 4)
void future_encoder_kernel(const float* __restrict__ h,
                           float* __restrict__ out,
                           int ntok) {
    __shared__ float scp[4 * SCP];     // per-wave partial scores [w][m][j]
    __shared__ float wtsT[JW * G];     // normalized weights, transposed [j][i]

    // XCD swizzle: contiguous 128-block chunk per XCD (~4 MiB working set = L2)
    int bid = blockIdx.x, nblk = gridDim.x, lb = bid;
    if ((nblk & 7) == 0) { int per = nblk >> 3; lb = (bid & 7) * per + (bid >> 3); }

    const int tid  = threadIdx.x;
    const int w    = tid >> 6;
    const int lane = tid & 63;
    const int t0   = lb * G;
    const int s0   = t0 & (S_CONST - 1);
    const int jlim = (S_CONST - 2) - s0;     // max in-sequence j

    // ---------- Phase 1: banded scores, wave w owns dims [w*256, w*256+256) ----------
    {
        const int d0 = w * 256;
        const int m  = lane & 15;            // A: token row / B: band row (within tile)
        const int kq = (lane >> 4) * 8;      // k-chunk within K=32 step
        const float* ap = h + (size_t)(t0 + (m < G ? m : G - 1)) * D + d0 + kq;
        const float* bp0, *bp1, *bp2;
        {
            int r0 = t0 + 1 +  0 + m;  if (r0 >= ntok) r0 = ntok - 1;
            int r1 = t0 + 1 + 16 + m;  if (r1 >= ntok) r1 = ntok - 1;
            int r2 = t0 + 1 + 32 + m;  if (r2 >= ntok) r2 = ntok - 1;
            bp0 = h + (size_t)r0 * D + d0 + kq;
            bp1 = h + (size_t)r1 * D + d0 + kq;
            bp2 = h + (size_t)r2 * D + d0 + kq;
        }

        f32x4 acc[JT] = {{0,0,0,0},{0,0,0,0},{0,0,0,0}};
        #pragma unroll 2
        for (int kk = 0; kk < 8; ++kk) {
            const int o = kk * 32;
            half8 ah, al;  cvt8(ap + o, ah, al);

            half8 bh, bl;
            cvt8(bp0 + o, bh, bl);
            acc[0] = __builtin_amdgcn_mfma_f32_16x16x32_f16(ah, bh, acc[0], 0, 0, 0);
            acc[0] = __builtin_amdgcn_mfma_f32_16x16x32_f16(ah, bl, acc[0], 0, 0, 0);
            acc[0] = __builtin_amdgcn_mfma_f32_16x16x32_f16(al, bh, acc[0], 0, 0, 0);
            cvt8(bp1 + o, bh, bl);
            acc[1] = __builtin_amdgcn_mfma_f32_16x16x32_f16(ah, bh, acc[1], 0, 0, 0);
            acc[1] = __builtin_amdgcn_mfma_f32_16x16x32_f16(ah, bl, acc[1], 0, 0, 0);
            acc[1] = __builtin_amdgcn_mfma_f32_16x16x32_f16(al, bh, acc[1], 0, 0, 0);
            cvt8(bp2 + o, bh, bl);
            acc[2] = __builtin_amdgcn_mfma_f32_16x16x32_f16(ah, bh, acc[2], 0, 0, 0);
            acc[2] = __builtin_amdgcn_mfma_f32_16x16x32_f16(ah, bl, acc[2], 0, 0, 0);
            acc[2] = __builtin_amdgcn_mfma_f32_16x16x32_f16(al, bh, acc[2], 0, 0, 0);
        }

        // C layout: col = lane&15 (j within tile), row = (lane>>4)*4 + reg (token)
        const int mr = (lane >> 4) * 4;
        #pragma unroll
        for (int t = 0; t < JT; ++t) {
            #pragma unroll
            for (int r = 0; r < 4; ++r) {
                int mm = mr + r;
                if (mm < G) scp[w * SCP + mm * 49 + t * 16 + m] = acc[t][r];
            }
        }
    }
    __syncthreads();

    // ---------- Phase 1.5: reduce 4 partials + softmax -> wtsT[j][i] ----------
    {
        const int i   = tid >> 5;      // token 0..7
        const int sub = tid & 31;
        const int j0  = sub;
        const int j1  = 32 + sub;      // only sub<16 meaningful

        const int rb = i * 49;
        float sa = scp[0*SCP + rb + j0] + scp[1*SCP + rb + j0]
                 + scp[2*SCP + rb + j0] + scp[3*SCP + rb + j0];
        bool va = (j0 >= i) && (j0 <= i + 31) && (j0 <= jlim);
        float v0 = va ? sa : -1e9f;

        float v1 = -1e9f; bool vb = false;
        if (sub < 16) {
            float sb = scp[0*SCP + rb + j1] + scp[1*SCP + rb + j1]
                     + scp[2*SCP + rb + j1] + scp[3*SCP + rb + j1];
            vb = (j1 >= i) && (j1 <= i + 31) && (j1 <= jlim);
            v1 = vb ? sb : -1e9f;
        }

        float mx = fmaxf(v0, v1);
        #pragma unroll
        for (int s = 1; s < 32; s <<= 1) mx = fmaxf(mx, __shfl_xor(mx, s, 32));

        float e0 = __expf(v0 - mx);
        float e1 = (sub < 16) ? __expf(v1 - mx) : 0.f;
        float sm = e0 + e1;
        #pragma unroll
        for (int s = 1; s < 32; s <<= 1) sm += __shfl_xor(sm, s, 32);

        const float inv = 1.0f / sm;   // empty tokens handled by valid masks below
        wtsT[j0 * G + i] = va ? e0 * inv : 0.f;
        if (sub < 16) wtsT[j1 * G + i] = vb ? e1 * inv : 0.f;
    }
    __syncthreads();

    // ---------- Phase 2: PV fp32, D-split: wave w dims [w*256,+256), 4 dims/lane ----
    {
        const int d = w * 256 + lane * 4;
        const float* fp = h + (size_t)(t0 + 1) * D + d;
        const int j2 = min(JMAX, jlim);

        float4 acc[G] = {};
        #pragma unroll 2
        for (int j = 0; j <= j2; ++j, fp += D) {
            float4 f  = *(const float4*)fp;
            float4 wa = *(const float4*)&wtsT[j * G];
            float4 wb = *(const float4*)&wtsT[j * G + 4];
            const float wgt[G] = {wa.x, wa.y, wa.z, wa.w, wb.x, wb.y, wb.z, wb.w};
            #pragma unroll
            for (int i = 0; i < G; ++i) {
                acc[i].x += wgt[i] * f.x;
                acc[i].y += wgt[i] * f.y;
                acc[i].z += wgt[i] * f.z;
                acc[i].w += wgt[i] * f.w;
            }
        }

        float* op = out + (size_t)t0 * D + d;
        #pragma unroll
        for (int i = 0; i < G; ++i) *(float4*)(op + (size_t)i * D) = acc[i];
    }
}

extern "C" void kernel_launch(void* const* d_in, const int* in_sizes, int n_in,
                              void* d_out, int out_size, void* d_ws, size_t ws_size,
                              hipStream_t stream) {
    const float* h = (const float*)d_in[0];
    float* out = (float*)d_out;
    const int ntok = in_sizes[0] / D;        // 8192
    const int blocks = ntok / G;             // 1024
    future_encoder_kernel<<<blocks, 256, 0, stream>>>(h, out, ntok);
}